// Round 2
// baseline (1068.890 us; speedup 1.0000x reference)
//
#include <hip/hip_runtime.h>

#define BB 128
#define TT 1024
#define II 100
#define HH 200

// ---------------------------------------------------------------------------
// Phase 1: xp[r][j] = b_ih[j] + b_hh[j] + sum_i x[r][i] * W_ih[j][i]
// Written into the hiddens region of d_out. One block = 256 threads handles
// 128 consecutive rows; W_ih row j in registers of thread j (100 VGPRs).
// ---------------------------------------------------------------------------
__global__ __launch_bounds__(256, 1) void rnn_xproj(
    const float* __restrict__ x, const float* __restrict__ Wih,
    const float* __restrict__ bih, const float* __restrict__ bhh,
    float* __restrict__ hid)
{
    __shared__ __align__(16) float xs[128 * II];  // 51.2 KB
    const int tid = threadIdx.x;
    const int j = tid;
    const int jl = (j < HH) ? j : (HH - 1);

    float w[II];
    const float4* wrow = (const float4*)(Wih + jl * II);
#pragma unroll
    for (int kk = 0; kk < II / 4; ++kk) {
        float4 v = wrow[kk];
        w[4 * kk + 0] = v.x; w[4 * kk + 1] = v.y;
        w[4 * kk + 2] = v.z; w[4 * kk + 3] = v.w;
    }
    const float bias = bih[jl] + bhh[jl];

    const long long r0 = (long long)blockIdx.x * 128;
    const float4* src = (const float4*)(x + r0 * II);
    float4* dst = (float4*)xs;
    for (int p = tid; p < 128 * II / 4; p += 256) dst[p] = src[p];
    __syncthreads();

    for (int row = 0; row < 128; ++row) {
        float acc0 = 0.f, acc1 = 0.f, acc2 = 0.f, acc3 = 0.f;
        const float4* xr = (const float4*)(xs + row * II);
#pragma unroll
        for (int kk = 0; kk < II / 4; ++kk) {
            float4 v = xr[kk];
            acc0 += w[4 * kk + 0] * v.x; acc1 += w[4 * kk + 1] * v.y;
            acc2 += w[4 * kk + 2] * v.z; acc3 += w[4 * kk + 3] * v.w;
        }
        if (j < HH)
            hid[(r0 + row) * HH + j] = bias + ((acc0 + acc1) + (acc2 + acc3));
    }
}

// ---------------------------------------------------------------------------
// Phase 2: serial recurrence. One block per batch element (128 blocks),
// 512 threads. Thread pair (2j, 2j+1) splits the row-j dot product:
// each holds 100 W_hh floats (25 float4 = 100 VGPRs -> guaranteed resident
// under the 256-VGPR cap of launch_bounds(512,2)). Partials combine with
// one __shfl_xor. xp for step t+1 is prefetched before the FMA loop.
// h double-buffered in LDS (2-address broadcast reads, conflict-free).
// ---------------------------------------------------------------------------
__global__ __launch_bounds__(512, 2) void rnn_recur(
    const float* __restrict__ Whh, float* __restrict__ hid)
{
    __shared__ __align__(16) float hbuf[2][208];
    const int tid  = threadIdx.x;
    const int half = tid & 1;        // which 100-wide K-slice
    const int j    = tid >> 1;       // output column, 0..255 (active < 200)
    const bool act = (j < HH);
    const int  jl  = act ? j : (HH - 1);

    float4 w[25];
    const float4* wrow = (const float4*)(Whh + jl * HH + 100 * half);
#pragma unroll
    for (int kk = 0; kk < 25; ++kk) w[kk] = wrow[kk];

    if (tid < HH) hbuf[0][tid] = 0.f;
    __syncthreads();

    float* rowp = hid + (long long)blockIdx.x * TT * HH;
    float xpv = (act && half == 0) ? rowp[j] : 0.f;   // xp for t=0
    int cur = 0;

    for (int t = 0; t < TT; ++t) {
        // prefetch next step's xp while the dot product runs
        float xpn = 0.f;
        if (act && half == 0 && t + 1 < TT) xpn = rowp[HH + j];

        const float4* hr = (const float4*)(hbuf[cur] + 100 * half);
        float a0 = 0.f, a1 = 0.f, a2 = 0.f, a3 = 0.f;
#pragma unroll
        for (int kk = 0; kk < 25; ++kk) {
            float4 v = hr[kk];
            a0 += w[kk].x * v.x; a1 += w[kk].y * v.y;
            a2 += w[kk].z * v.z; a3 += w[kk].w * v.w;
        }
        float p = (a0 + a1) + (a2 + a3);
        p += __shfl_xor(p, 1, 64);   // combine the two K-halves

        if (act && half == 0) {
            float hv = fmaxf(xpv + p, 0.f);
            rowp[j] = hv;            // hiddens output (fire-and-forget)
            hbuf[cur ^ 1][j] = hv;   // next step's input
        }
        __syncthreads();
        cur ^= 1; xpv = xpn; rowp += HH;
    }
}

// ---------------------------------------------------------------------------
// Phase 3: o[r] = sum_j W_out[j]*h[r][j] + b_out. 2048 blocks x 64 rows;
// one wave per row-slot, W_out cached in registers, shuffle reduction.
// ---------------------------------------------------------------------------
__global__ __launch_bounds__(256) void rnn_out(
    const float* __restrict__ hid, const float* __restrict__ Wout,
    const float* __restrict__ bout, float* __restrict__ out)
{
    const int wave = threadIdx.x >> 6;
    const int lane = threadIdx.x & 63;

    float wv[4];
#pragma unroll
    for (int m = 0; m < 4; ++m) {
        int idx = lane + 64 * m;
        wv[m] = (idx < HH) ? Wout[idx] : 0.f;
    }
    const float bo = bout[0];

    const long long rbase = (long long)blockIdx.x * 64;
#pragma unroll 1
    for (int rr = wave; rr < 64; rr += 4) {
        const float* hr = hid + (rbase + rr) * HH;
        float p = 0.f;
#pragma unroll
        for (int m = 0; m < 4; ++m) {
            int idx = lane + 64 * m;
            if (idx < HH) p += wv[m] * hr[idx];
        }
#pragma unroll
        for (int off = 32; off; off >>= 1) p += __shfl_down(p, off, 64);
        if (lane == 0) out[rbase + rr] = p + bo;
    }
}

extern "C" void kernel_launch(void* const* d_in, const int* in_sizes, int n_in,
                              void* d_out, int out_size, void* d_ws, size_t ws_size,
                              hipStream_t stream)
{
    const float* x    = (const float*)d_in[0];  // [128,1024,100]
    const float* Wih  = (const float*)d_in[1];  // [200,100]
    const float* Whh  = (const float*)d_in[2];  // [200,200]
    const float* bih  = (const float*)d_in[3];  // [200]
    const float* bhh  = (const float*)d_in[4];  // [200]
    const float* Wout = (const float*)d_in[5];  // [1,200]
    const float* bout = (const float*)d_in[6];  // [1]

    float* out = (float*)d_out;                 // [128*1024] outputs first
    float* hid = out + (long long)BB * TT;      // [128*1024*200] hiddens

    rnn_xproj<<<(BB * TT) / 128, 256, 0, stream>>>(x, Wih, bih, bhh, hid);
    rnn_recur<<<BB, 512, 0, stream>>>(Whh, hid);
    rnn_out<<<(BB * TT) / 64, 256, 0, stream>>>(hid, Wout, bout, out);
}